// Round 10
// baseline (584.086 us; speedup 1.0000x reference)
//
#include <hip/hip_runtime.h>

typedef unsigned int uint;
typedef __fp16 half2_t __attribute__((ext_vector_type(2)));
typedef __fp16 half8_t __attribute__((ext_vector_type(8)));
typedef float floatx4 __attribute__((ext_vector_type(4)));

#define SEQ 512
#define BATCH 128
#define HID 128
#define NTAG 32
#define START_TAG 30
#define END_TAG 31

__device__ __forceinline__ float fdot2(uint a, uint b, float c) {
  return __builtin_amdgcn_fdot2(__builtin_bit_cast(half2_t, a),
                                __builtin_bit_cast(half2_t, b), c, false);
}
__device__ __forceinline__ uint packh2(float a, float b) {
  half2_t h = __builtin_amdgcn_cvt_pkrtz(a, b);
  return __builtin_bit_cast(uint, h);
}
__device__ __forceinline__ float frcp(float x) { return __builtin_amdgcn_rcpf(x); }
__device__ __forceinline__ float fsig(float x) { return frcp(1.f + __expf(-x)); }
__device__ __forceinline__ float ftanh(float x) { return 1.f - 2.f * frcp(1.f + __expf(2.f * x)); }
__device__ __forceinline__ float fexp2(float x) { return __builtin_amdgcn_exp2f(x); }
__device__ __forceinline__ float flog2(float x) { return __builtin_amdgcn_logf(x); }

// ---------------------------------------------------------------------------
// prep (unchanged from R8)
// ---------------------------------------------------------------------------
__global__ __launch_bounds__(256) void prep_kernel(
    const float* __restrict__ Wihf, const float* __restrict__ Whhf,
    const float* __restrict__ bihf, const float* __restrict__ bhhf,
    const float* __restrict__ Wihb, const float* __restrict__ Whhb,
    const float* __restrict__ bihb, const float* __restrict__ bhhb,
    const float* __restrict__ Wout,
    uint* __restrict__ wihI, uint* __restrict__ whh,
    uint* __restrict__ woutp, float* __restrict__ biasI)
{
  int idx = blockIdx.x * 256 + threadIdx.x;
  if (idx < 65536) {
    int d = idx >> 15, rem = idx & 32767;
    int n = rem >> 6, dw = rem & 63;
    int m = n >> 2, q = n & 3;
    int g = q * 128 + m;
    const float* W = d ? Wihb : Wihf;
    wihI[idx] = packh2(W[g * 128 + 2 * dw], W[g * 128 + 2 * dw + 1]);
  }
  int i2 = idx - 65536;
  if (i2 >= 0 && i2 < 65536) {
    int d = i2 >> 15, rem = i2 & 32767;
    int g = rem >> 6, dw = rem & 63;
    const float* W = d ? Whhb : Whhf;
    whh[i2] = packh2(W[g * 128 + 2 * dw], W[g * 128 + 2 * dw + 1]);
  }
  int i3 = idx - 131072;
  if (i3 >= 0 && i3 < 4096) {
    int k = i3 >> 7, dw = i3 & 127;
    float a, b2;
    if (dw < 64) { a = Wout[k * 256 + 2 * dw]; b2 = Wout[k * 256 + 2 * dw + 1]; }
    else { int j = dw - 64; a = Wout[k * 256 + 128 + 2 * j]; b2 = Wout[k * 256 + 128 + 2 * j + 1]; }
    woutp[i3] = packh2(a, b2);
  }
  int i4 = idx - 135168;
  if (i4 >= 0 && i4 < 1024) {
    int d = i4 >> 9, n = i4 & 511;
    int g = (n & 3) * 128 + (n >> 2);
    biasI[i4] = d ? (bihb[g] + bhhb[g]) : (bihf[g] + bhhf[g]);
  }
}

// ---------------------------------------------------------------------------
// gemmx (unchanged from R8)
// ---------------------------------------------------------------------------
__global__ __launch_bounds__(256, 2) void gemmx_kernel(
    const int* __restrict__ sentence, const float* __restrict__ embed,
    const uint* __restrict__ wihI, const float* __restrict__ biasI,
    uint* __restrict__ gatex, int chunk)
{
  int blk = blockIdx.x;
  int tl = blk & 127, nb = (blk >> 7) & 3, d = blk >> 9;
  int t = chunk * 128 + tl;
  int s = d ? (511 - t) : t;
  __shared__ int tok[128];
  int tid = threadIdx.x;
  if (tid < 128) tok[tid] = sentence[tid * SEQ + s];
  __syncthreads();

  int w = tid >> 6, lane = tid & 63;
  int q = lane >> 4, r = lane & 15;
  int wr = w >> 1, wc = w & 1;
  int r0 = wr * 64;
  int c0 = nb * 128 + wc * 64;

  floatx4 acc[4][4];
#pragma unroll
  for (int i = 0; i < 4; ++i)
#pragma unroll
    for (int j = 0; j < 4; ++j) acc[i][j] = (floatx4){0.f, 0.f, 0.f, 0.f};

  const float4* aptr[4];
#pragma unroll
  for (int i = 0; i < 4; ++i)
    aptr[i] = (const float4*)(embed + (size_t)tok[r0 + i * 16 + r] * HID) + q * 2;
  const uint4* bptr[4];
#pragma unroll
  for (int j = 0; j < 4; ++j)
    bptr[j] = (const uint4*)(wihI + ((size_t)d * 512 + c0 + j * 16 + r) * 64) + q;

#pragma unroll
  for (int kc = 0; kc < 4; ++kc) {
    half8_t af[4], bf[4];
#pragma unroll
    for (int i = 0; i < 4; ++i) {
      float4 x0 = aptr[i][kc * 8];
      float4 x1 = aptr[i][kc * 8 + 1];
      uint4 u;
      u.x = packh2(x0.x, x0.y); u.y = packh2(x0.z, x0.w);
      u.z = packh2(x1.x, x1.y); u.w = packh2(x1.z, x1.w);
      af[i] = __builtin_bit_cast(half8_t, u);
    }
#pragma unroll
    for (int j = 0; j < 4; ++j)
      bf[j] = __builtin_bit_cast(half8_t, bptr[j][kc * 4]);
#pragma unroll
    for (int i = 0; i < 4; ++i)
#pragma unroll
      for (int j = 0; j < 4; ++j)
        acc[i][j] = __builtin_amdgcn_mfma_f32_16x16x32_f16(af[i], bf[j], acc[i][j], 0, 0, 0);
  }

  __fp16* gat = ((__fp16*)gatex) + (size_t)d * 16384 * 512;
#pragma unroll
  for (int j = 0; j < 4; ++j) {
    int n = c0 + j * 16 + r;
    float bb = biasI[d * 512 + n];
#pragma unroll
    for (int i = 0; i < 4; ++i) {
      int rb = r0 + i * 16 + q * 4;
#pragma unroll
      for (int reg = 0; reg < 4; ++reg) {
        float v = acc[i][j][reg] + bb;
        gat[((size_t)(tl * 128 + rb + reg)) * 512 + n] = (__fp16)v;
      }
    }
  }
}

// ---------------------------------------------------------------------------
// LSTM recurrence. One WG per (d,b); grid = 256 = 1 block/CU.
// R10: hist is GENUINELY 96 KB (384 rows, offset roff=(chunk>>8)&256 is 0 at
// runtime but unprovable at compile time) -> compiler sees 1 block/CU max ->
// occupancy target 1 wave/EU -> 512-VGPR budget -> wreg (128 VGPRs) stays
// register-resident instead of being re-fetched from L2 every step (R8/R9:
// VGPR_Count=84, ~1500 cyc/step of weight reload traffic).
// ---------------------------------------------------------------------------
__global__ __launch_bounds__(256, 1) __attribute__((amdgpu_waves_per_eu(1, 1)))
void lstm_kernel(
    const uint* __restrict__ gatex, const uint* __restrict__ whh,
    const float* __restrict__ h0, const float* __restrict__ c0,
    float* __restrict__ statec, uint* __restrict__ hh, int chunk)
{
  const int wg = blockIdx.x;
  const int d = wg >> 7, b = wg & 127;
  const int tid = threadIdx.x;
  const int w = tid >> 6, lane = tid & 63;
  const int hp = lane >> 5, r = lane & 31;
  const int m = w * 32 + r;

  __shared__ __align__(16) __fp16 hist[384][128];   // 96 KB: caps 1 block/CU
  const int roff = (chunk >> 8) & 256;              // == 0, unprovable

  const uint4* wh4 = (const uint4*)(whh + (size_t)d * 512 * 64);
  uint4 wreg[4][8];
#pragma unroll
  for (int q = 0; q < 4; ++q) {
    const uint4* row = wh4 + (q * 128 + m) * 16 + hp * 8;
#pragma unroll
    for (int i = 0; i < 8; ++i) wreg[q][i] = row[i];
  }

  float c = (chunk == 0) ? c0[(size_t)(d * 128 + b) * 128 + m]
                         : statec[(size_t)(d * 128 + b) * 128 + m];

  if (tid < 64) {
    uint* h127 = (uint*)&hist[roff + 127][0];
    if (chunk == 0) {
      float2 hv = ((const float2*)(h0 + (size_t)(d * 128 + b) * 128))[tid];
      h127[tid] = packh2(hv.x, hv.y);
    } else {
      int sprev = d ? (511 - (chunk * 128 - 1)) : (chunk * 128 - 1);
      h127[tid] = hh[((size_t)(d * 512 + sprev) * 128 + b) * 64 + tid];
    }
  }
  const uint* gx0 = gatex + (size_t)d * 4194304 + (size_t)b * 256 + 2 * m;
  uint2 gx = *(const uint2*)(gx0);
  __syncthreads();

  for (int tl = 0; tl < 128; ++tl) {
    uint2 gxn = gx;
    if (tl < 127) gxn = *(const uint2*)(gx0 + (size_t)(tl + 1) * 32768);

    float a0 = 0.f, a1 = 0.f, a2 = 0.f, a3 = 0.f;
    const uint4* z4 = (const uint4*)(&hist[roff + ((tl + 127) & 127)][hp * 64]);
#pragma unroll
    for (int i = 0; i < 8; ++i) {
      uint4 z = z4[i];
      a0 = fdot2(z.x, wreg[0][i].x, a0);
      a0 = fdot2(z.y, wreg[0][i].y, a0);
      a0 = fdot2(z.z, wreg[0][i].z, a0);
      a0 = fdot2(z.w, wreg[0][i].w, a0);
      a1 = fdot2(z.x, wreg[1][i].x, a1);
      a1 = fdot2(z.y, wreg[1][i].y, a1);
      a1 = fdot2(z.z, wreg[1][i].z, a1);
      a1 = fdot2(z.w, wreg[1][i].w, a1);
      a2 = fdot2(z.x, wreg[2][i].x, a2);
      a2 = fdot2(z.y, wreg[2][i].y, a2);
      a2 = fdot2(z.z, wreg[2][i].z, a2);
      a2 = fdot2(z.w, wreg[2][i].w, a2);
      a3 = fdot2(z.x, wreg[3][i].x, a3);
      a3 = fdot2(z.y, wreg[3][i].y, a3);
      a3 = fdot2(z.z, wreg[3][i].z, a3);
      a3 = fdot2(z.w, wreg[3][i].w, a3);
    }
    a0 += __shfl_xor(a0, 32);
    a1 += __shfl_xor(a1, 32);
    a2 += __shfl_xor(a2, 32);
    a3 += __shfl_xor(a3, 32);

    half2_t g01 = __builtin_bit_cast(half2_t, gx.x);
    half2_t g23 = __builtin_bit_cast(half2_t, gx.y);
    a0 += (float)g01[0];
    a1 += (float)g01[1];
    a2 += (float)g23[0];
    a3 += (float)g23[1];

    float ig = fsig(a0);
    float fg = fsig(a1);
    float gg = ftanh(a2);
    float og = fsig(a3);
    c = fg * c + ig * gg;
    float hv = og * ftanh(c);

    if (hp == 0) hist[roff + tl][m] = (__fp16)hv;
    gx = gxn;
    __syncthreads();
  }

  statec[(size_t)(d * 128 + b) * 128 + m] = c;

  int base = chunk * 128;
  for (int i = tid; i < 2048; i += 256) {
    int sl = i >> 4, q4 = i & 15;
    int s = d ? (511 - (base + sl)) : (base + sl);
    *(uint4*)(&hh[((size_t)(d * 512 + s) * 128 + b) * 64 + q4 * 4]) =
        *(const uint4*)((const uint*)&hist[roff + sl][0] + q4 * 4);
  }
}

// ---------------------------------------------------------------------------
// Output projection (unchanged from R8)
// ---------------------------------------------------------------------------
__global__ __launch_bounds__(256) void outproj_kernel(
    const uint* __restrict__ hh, const uint* __restrict__ woutp,
    const float* __restrict__ bout, float* __restrict__ feats)
{
  __shared__ __align__(16) uint4 zrow[8][32];
  __shared__ __align__(16) uint4 wlds[32][32];
  int tid = threadIdx.x;
  for (int j = tid; j < 1024; j += 256) {
    int k = j >> 5, i = j & 31;
    wlds[i][k] = ((const uint4*)woutp)[j];
  }
  int rl = tid >> 5, q = tid & 31;
  int row = blockIdx.x * 8 + rl;
  int b = row >> 9, s = row & 511;
  const uint4* hf4 = (const uint4*)(hh + ((size_t)s * BATCH + b) * 64);
  const uint4* hb4 = (const uint4*)(hh + ((size_t)(SEQ + s) * BATCH + b) * 64);
  zrow[rl][q] = (q < 16) ? hf4[q] : hb4[q - 16];
  __syncthreads();
  int k = q;
  float acc = bout[k];
#pragma unroll
  for (int i = 0; i < 32; ++i) {
    uint4 z = zrow[rl][i];
    uint4 wv = wlds[i][k];
    acc = fdot2(z.x, wv.x, acc);
    acc = fdot2(z.y, wv.y, acc);
    acc = fdot2(z.z, wv.z, acc);
    acc = fdot2(z.w, wv.w, acc);
  }
  feats[(size_t)row * 32 + k] = acc;
}

// ---------------------------------------------------------------------------
// CRF numerator (unchanged)
// ---------------------------------------------------------------------------
__global__ __launch_bounds__(64) void crf_num_kernel(
    const int* __restrict__ tags, const float* __restrict__ feats,
    const float* __restrict__ trans, float* __restrict__ num)
{
  int b = blockIdx.x, l = threadIdx.x;
  const int* tb = tags + b * SEQ;
  float acc = 0.f;
  for (int s = l; s < SEQ; s += 64) {
    int tg = tb[s];
    int pv = (s == 0) ? START_TAG : tb[s - 1];
    acc += trans[pv * NTAG + tg] + feats[((size_t)b * SEQ + s) * NTAG + tg];
  }
#pragma unroll
  for (int msk = 1; msk < 64; msk <<= 1) acc += __shfl_xor(acc, msk);
  if (l == 0) num[b] = acc + trans[tb[SEQ - 1] * NTAG + END_TAG];
}

// ---------------------------------------------------------------------------
// CRF stage A (unchanged from R8)
// ---------------------------------------------------------------------------
__global__ __launch_bounds__(64) void crf_seg_kernel(
    const float* __restrict__ feats, const float* __restrict__ trans,
    uint* __restrict__ segP, float* __restrict__ segL)
{
  const float L2E = 1.4426950408889634f;
  int blk = blockIdx.x;
  int b = blk >> 5, j = blk & 31;
  int tstart = 1 + 16 * j;
  int nsteps = (j == 31) ? 15 : 16;
  int lane = threadIdx.x;
  int c = lane & 15, q = lane >> 4;

  half8_t afr[2];
#pragma unroll
  for (int rt = 0; rt < 2; ++rt) {
    const float* trow = trans + (rt * 16 + c) * 32 + q * 8;
    float e[8];
#pragma unroll
    for (int i = 0; i < 8; ++i) e[i] = fexp2(trow[i] * L2E);
    uint4 u;
    u.x = packh2(e[0], e[1]); u.y = packh2(e[2], e[3]);
    u.z = packh2(e[4], e[5]); u.w = packh2(e[6], e[7]);
    afr[rt] = __builtin_bit_cast(half8_t, u);
  }
  half8_t bfr[2];
#pragma unroll
  for (int ct = 0; ct < 2; ++ct) {
    uint4 u;
    uint vals[8];
#pragma unroll
    for (int i = 0; i < 8; ++i)
      vals[i] = ((q * 8 + i) == (ct * 16 + c)) ? 0x3C00u : 0u;
    u.x = vals[0] | (vals[1] << 16);
    u.y = vals[2] | (vals[3] << 16);
    u.z = vals[4] | (vals[5] << 16);
    u.w = vals[6] | (vals[7] << 16);
    bfr[ct] = __builtin_bit_cast(half8_t, u);
  }

  __shared__ __fp16 P16[32 * 36];

  const float* fb = feats + ((size_t)b * SEQ + tstart) * NTAG;
  float Lacc = 0.f;
  float4 pre0 = *(const float4*)(fb + q * 4);
  float4 pre1 = *(const float4*)(fb + 16 + q * 4);

  for (int s = 0; s < nsteps; ++s) {
    float4 f0 = pre0, f1 = pre1;
    if (s + 1 < nsteps) {
      pre0 = *(const float4*)(fb + (s + 1) * 32 + q * 4);
      pre1 = *(const float4*)(fb + (s + 1) * 32 + 16 + q * 4);
    }
    floatx4 z4 = (floatx4){0.f, 0.f, 0.f, 0.f};
    floatx4 c00 = __builtin_amdgcn_mfma_f32_16x16x32_f16(afr[0], bfr[0], z4, 0, 0, 0);
    floatx4 c01 = __builtin_amdgcn_mfma_f32_16x16x32_f16(afr[0], bfr[1], z4, 0, 0, 0);
    floatx4 c10 = __builtin_amdgcn_mfma_f32_16x16x32_f16(afr[1], bfr[0], z4, 0, 0, 0);
    floatx4 c11 = __builtin_amdgcn_mfma_f32_16x16x32_f16(afr[1], bfr[1], z4, 0, 0, 0);
    float pf0[4], pf1[4];
    pf0[0] = fexp2(f0.x * L2E); pf0[1] = fexp2(f0.y * L2E);
    pf0[2] = fexp2(f0.z * L2E); pf0[3] = fexp2(f0.w * L2E);
    pf1[0] = fexp2(f1.x * L2E); pf1[1] = fexp2(f1.y * L2E);
    pf1[2] = fexp2(f1.z * L2E); pf1[3] = fexp2(f1.w * L2E);
    float v00[4], v01[4], v10[4], v11[4];
#pragma unroll
    for (int rg = 0; rg < 4; ++rg) {
      v00[rg] = c00[rg] * pf0[rg];
      v01[rg] = c01[rg] * pf0[rg];
      v10[rg] = c10[rg] * pf1[rg];
      v11[rg] = c11[rg] * pf1[rg];
    }
    float mx = 0.f;
#pragma unroll
    for (int rg = 0; rg < 4; ++rg)
      mx = fmaxf(mx, fmaxf(fmaxf(v00[rg], v01[rg]), fmaxf(v10[rg], v11[rg])));
    uint ub = (uint)__builtin_amdgcn_readfirstlane((int)__builtin_bit_cast(uint, mx));
    int e = (int)((ub >> 23) & 255u);
    Lacc += (float)(e - 127);
    float sc = __builtin_bit_cast(float, (uint)((254 - e) << 23));

    __syncthreads();
    {
      uint2 wv2;
      wv2.x = packh2(v00[0] * sc, v00[1] * sc);
      wv2.y = packh2(v00[2] * sc, v00[3] * sc);
      *(uint2*)(&P16[c * 36 + q * 4]) = wv2;
      wv2.x = packh2(v10[0] * sc, v10[1] * sc);
      wv2.y = packh2(v10[2] * sc, v10[3] * sc);
      *(uint2*)(&P16[c * 36 + 16 + q * 4]) = wv2;
      wv2.x = packh2(v01[0] * sc, v01[1] * sc);
      wv2.y = packh2(v01[2] * sc, v01[3] * sc);
      *(uint2*)(&P16[(16 + c) * 36 + q * 4]) = wv2;
      wv2.x = packh2(v11[0] * sc, v11[1] * sc);
      wv2.y = packh2(v11[2] * sc, v11[3] * sc);
      *(uint2*)(&P16[(16 + c) * 36 + 16 + q * 4]) = wv2;
    }
    __syncthreads();
    {
      uint2 lo0 = *(const uint2*)(&P16[c * 36 + q * 8]);
      uint2 hi0 = *(const uint2*)(&P16[c * 36 + q * 8 + 4]);
      uint4 u0; u0.x = lo0.x; u0.y = lo0.y; u0.z = hi0.x; u0.w = hi0.y;
      bfr[0] = __builtin_bit_cast(half8_t, u0);
      uint2 lo1 = *(const uint2*)(&P16[(16 + c) * 36 + q * 8]);
      uint2 hi1 = *(const uint2*)(&P16[(16 + c) * 36 + q * 8 + 4]);
      uint4 u1; u1.x = lo1.x; u1.y = lo1.y; u1.z = hi1.x; u1.w = hi1.y;
      bfr[1] = __builtin_bit_cast(half8_t, u1);
    }
  }
  __syncthreads();
  uint* gp = segP + (size_t)blk * 512;
  if (lane < 32) {
    int i = lane;
#pragma unroll
    for (int tp = 0; tp < 16; ++tp) {
      uint lo = (uint)__builtin_bit_cast(unsigned short, P16[(2 * tp) * 36 + i]);
      uint hi = (uint)__builtin_bit_cast(unsigned short, P16[(2 * tp + 1) * 36 + i]);
      gp[i * 16 + tp] = lo | (hi << 16);
    }
  }
  if (lane == 0) segL[blk] = Lacc;
}

// ---------------------------------------------------------------------------
// CRF stage B (unchanged from R8)
// ---------------------------------------------------------------------------
__global__ __launch_bounds__(64) void crf_comb_kernel(
    const float* __restrict__ feats, const float* __restrict__ trans,
    const uint* __restrict__ segP, const float* __restrict__ segL,
    float* __restrict__ den)
{
  const float L2E = 1.4426950408889634f, LN2 = 0.6931471805599453f;
  int b = blockIdx.x, l = threadIdx.x;
  int i = l & 31, hp = l >> 5;
  const float* fb = feats + (size_t)b * SEQ * NTAG;

  float sT = 0.f;
  for (int p = 0; p < 32; ++p) sT += fexp2(trans[i * 32 + p] * L2E);
  float v = (1.f + sT) * fexp2(fb[i] * L2E);
  float L = -10000.f * L2E;

  float vo = __shfl_xor(v, 1);
  uint pv = (i & 1) ? packh2(vo, v) : packh2(v, vo);

  const uint* gp0 = segP + (size_t)b * 32 * 512 + i * 16 + hp * 8;
  uint4 ra = *(const uint4*)(gp0);
  uint4 rb = *(const uint4*)(gp0 + 4);

  for (int seg = 0; seg < 32; ++seg) {
    uint4 ca = ra, cb = rb;
    if (seg + 1 < 32) {
      ra = *(const uint4*)(gp0 + (seg + 1) * 512);
      rb = *(const uint4*)(gp0 + (seg + 1) * 512 + 4);
    }
    float g0 = __shfl(__builtin_bit_cast(float, pv), hp * 16 + 0);
    float g1 = __shfl(__builtin_bit_cast(float, pv), hp * 16 + 2);
    float g2 = __shfl(__builtin_bit_cast(float, pv), hp * 16 + 4);
    float g3 = __shfl(__builtin_bit_cast(float, pv), hp * 16 + 6);
    float g4 = __shfl(__builtin_bit_cast(float, pv), hp * 16 + 8);
    float g5 = __shfl(__builtin_bit_cast(float, pv), hp * 16 + 10);
    float g6 = __shfl(__builtin_bit_cast(float, pv), hp * 16 + 12);
    float g7 = __shfl(__builtin_bit_cast(float, pv), hp * 16 + 14);
    float acc = 0.f;
    acc = fdot2(__builtin_bit_cast(uint, g0), ca.x, acc);
    acc = fdot2(__builtin_bit_cast(uint, g1), ca.y, acc);
    acc = fdot2(__builtin_bit_cast(uint, g2), ca.z, acc);
    acc = fdot2(__builtin_bit_cast(uint, g3), ca.w, acc);
    acc = fdot2(__builtin_bit_cast(uint, g4), cb.x, acc);
    acc = fdot2(__builtin_bit_cast(uint, g5), cb.y, acc);
    acc = fdot2(__builtin_bit_cast(uint, g6), cb.z, acc);
    acc = fdot2(__builtin_bit_cast(uint, g7), cb.w, acc);
    float sm = acc + __shfl_xor(acc, 32);
    uint ub = (uint)__builtin_amdgcn_readfirstlane((int)__builtin_bit_cast(uint, sm));
    int e = (int)((ub >> 23) & 255u);
    L += (float)(e - 127) + segL[b * 32 + seg];
    float sc = __builtin_bit_cast(float, (uint)((254 - e) << 23));
    v = sm * sc;
    float vo2 = __shfl_xor(v, 1);
    pv = (i & 1) ? packh2(vo2, v) : packh2(v, vo2);
  }
  float wv = v * fexp2(trans[i * 32 + END_TAG] * L2E);
#pragma unroll
  for (int msk = 1; msk <= 16; msk <<= 1) wv += __shfl_xor(wv, msk);
  if (l == 0) den[b] = (L + flog2(wv)) * LN2;
}

__global__ __launch_bounds__(128) void final_kernel(
    const float* __restrict__ num, const float* __restrict__ den,
    float* __restrict__ out)
{
  int tid = threadIdx.x;
  float v = num[tid] - den[tid];
#pragma unroll
  for (int msk = 1; msk < 64; msk <<= 1) v += __shfl_xor(v, msk);
  __shared__ float tmp[2];
  if ((tid & 63) == 0) tmp[tid >> 6] = v;
  __syncthreads();
  if (tid == 0) out[0] = (tmp[0] + tmp[1]) * (1.f / 128.f);
}

// ---------------------------------------------------------------------------
// Workspace layout (bytes): same as R8 (~51.4 MB)
// ---------------------------------------------------------------------------
extern "C" void kernel_launch(void* const* d_in, const int* in_sizes, int n_in,
                              void* d_out, int out_size, void* d_ws, size_t ws_size,
                              hipStream_t stream)
{
  const int* sentence = (const int*)d_in[0];
  const int* tags = (const int*)d_in[1];
  const float* embed = (const float*)d_in[2];
  const float* Wihf = (const float*)d_in[3];
  const float* Whhf = (const float*)d_in[4];
  const float* bihf = (const float*)d_in[5];
  const float* bhhf = (const float*)d_in[6];
  const float* Wihb = (const float*)d_in[7];
  const float* Whhb = (const float*)d_in[8];
  const float* bihb = (const float*)d_in[9];
  const float* bhhb = (const float*)d_in[10];
  const float* Wout = (const float*)d_in[11];
  const float* bout = (const float*)d_in[12];
  const float* trans = (const float*)d_in[13];
  const float* h0 = (const float*)d_in[14];
  const float* c0 = (const float*)d_in[15];
  float* out = (float*)d_out;

  char* ws = (char*)d_ws;
  uint* wihI = (uint*)(ws + 0);
  uint* whh = (uint*)(ws + 262144);
  uint* woutp = (uint*)(ws + 524288);
  float* biasI = (float*)(ws + 540672);
  float* numb = (float*)(ws + 544768);
  float* denb = (float*)(ws + 545280);
  float* statec = (float*)(ws + 545792);
  uint* hh = (uint*)(ws + 1048576);
  uint* gatex = (uint*)(ws + 34603008);
  float* feats = (float*)(ws + 34603008);
  uint* segP = (uint*)(ws + 42991616);
  float* segL = (float*)(ws + 51380224);

  hipLaunchKernelGGL(prep_kernel, dim3(532), dim3(256), 0, stream,
                     Wihf, Whhf, bihf, bhhf, Wihb, Whhb, bihb, bhhb, Wout,
                     wihI, whh, woutp, biasI);
  for (int c = 0; c < 4; ++c) {
    hipLaunchKernelGGL(gemmx_kernel, dim3(1024), dim3(256), 0, stream,
                       sentence, embed, wihI, biasI, gatex, c);
    hipLaunchKernelGGL(lstm_kernel, dim3(256), dim3(256), 0, stream,
                       gatex, whh, h0, c0, statec, hh, c);
  }
  hipLaunchKernelGGL(outproj_kernel, dim3(8192), dim3(256), 0, stream,
                     hh, woutp, bout, feats);
  hipLaunchKernelGGL(crf_num_kernel, dim3(128), dim3(64), 0, stream,
                     tags, feats, trans, numb);
  hipLaunchKernelGGL(crf_seg_kernel, dim3(4096), dim3(64), 0, stream,
                     feats, trans, segP, segL);
  hipLaunchKernelGGL(crf_comb_kernel, dim3(128), dim3(64), 0, stream,
                     feats, trans, segP, segL, denb);
  hipLaunchKernelGGL(final_kernel, dim3(1), dim3(128), 0, stream,
                     numb, denb, out);
}

// Round 12
// 582.060 us; speedup vs baseline: 1.0035x; 1.0035x over previous
//
#include <hip/hip_runtime.h>

typedef unsigned int uint;
typedef __fp16 half2_t __attribute__((ext_vector_type(2)));
typedef __fp16 half8_t __attribute__((ext_vector_type(8)));
typedef float floatx4 __attribute__((ext_vector_type(4)));

#define SEQ 512
#define BATCH 128
#define HID 128
#define NTAG 32
#define START_TAG 30
#define END_TAG 31

__device__ __forceinline__ float fdot2(uint a, uint b, float c) {
  return __builtin_amdgcn_fdot2(__builtin_bit_cast(half2_t, a),
                                __builtin_bit_cast(half2_t, b), c, false);
}
__device__ __forceinline__ uint packh2(float a, float b) {
  half2_t h = __builtin_amdgcn_cvt_pkrtz(a, b);
  return __builtin_bit_cast(uint, h);
}
__device__ __forceinline__ float frcp(float x) { return __builtin_amdgcn_rcpf(x); }
__device__ __forceinline__ float fsig(float x) { return frcp(1.f + __expf(-x)); }
__device__ __forceinline__ float ftanh(float x) { return 1.f - 2.f * frcp(1.f + __expf(2.f * x)); }
__device__ __forceinline__ float fexp2(float x) { return __builtin_amdgcn_exp2f(x); }
__device__ __forceinline__ float flog2(float x) { return __builtin_amdgcn_logf(x); }

// ---------------------------------------------------------------------------
// prep (unchanged)
// ---------------------------------------------------------------------------
__global__ __launch_bounds__(256) void prep_kernel(
    const float* __restrict__ Wihf, const float* __restrict__ Whhf,
    const float* __restrict__ bihf, const float* __restrict__ bhhf,
    const float* __restrict__ Wihb, const float* __restrict__ Whhb,
    const float* __restrict__ bihb, const float* __restrict__ bhhb,
    const float* __restrict__ Wout,
    uint* __restrict__ wihI, uint* __restrict__ whh,
    uint* __restrict__ woutp, float* __restrict__ biasI)
{
  int idx = blockIdx.x * 256 + threadIdx.x;
  if (idx < 65536) {
    int d = idx >> 15, rem = idx & 32767;
    int n = rem >> 6, dw = rem & 63;
    int m = n >> 2, q = n & 3;
    int g = q * 128 + m;
    const float* W = d ? Wihb : Wihf;
    wihI[idx] = packh2(W[g * 128 + 2 * dw], W[g * 128 + 2 * dw + 1]);
  }
  int i2 = idx - 65536;
  if (i2 >= 0 && i2 < 65536) {
    int d = i2 >> 15, rem = i2 & 32767;
    int g = rem >> 6, dw = rem & 63;
    const float* W = d ? Whhb : Whhf;
    whh[i2] = packh2(W[g * 128 + 2 * dw], W[g * 128 + 2 * dw + 1]);
  }
  int i3 = idx - 131072;
  if (i3 >= 0 && i3 < 4096) {
    int k = i3 >> 7, dw = i3 & 127;
    float a, b2;
    if (dw < 64) { a = Wout[k * 256 + 2 * dw]; b2 = Wout[k * 256 + 2 * dw + 1]; }
    else { int j = dw - 64; a = Wout[k * 256 + 128 + 2 * j]; b2 = Wout[k * 256 + 128 + 2 * j + 1]; }
    woutp[i3] = packh2(a, b2);
  }
  int i4 = idx - 135168;
  if (i4 >= 0 && i4 < 1024) {
    int d = i4 >> 9, n = i4 & 511;
    int g = (n & 3) * 128 + (n >> 2);
    biasI[i4] = d ? (bihb[g] + bhhb[g]) : (bihf[g] + bhhf[g]);
  }
}

// ---------------------------------------------------------------------------
// gemmx (unchanged)
// ---------------------------------------------------------------------------
__global__ __launch_bounds__(256, 2) void gemmx_kernel(
    const int* __restrict__ sentence, const float* __restrict__ embed,
    const uint* __restrict__ wihI, const float* __restrict__ biasI,
    uint* __restrict__ gatex, int chunk)
{
  int blk = blockIdx.x;
  int tl = blk & 127, nb = (blk >> 7) & 3, d = blk >> 9;
  int t = chunk * 128 + tl;
  int s = d ? (511 - t) : t;
  __shared__ int tok[128];
  int tid = threadIdx.x;
  if (tid < 128) tok[tid] = sentence[tid * SEQ + s];
  __syncthreads();

  int w = tid >> 6, lane = tid & 63;
  int q = lane >> 4, r = lane & 15;
  int wr = w >> 1, wc = w & 1;
  int r0 = wr * 64;
  int c0 = nb * 128 + wc * 64;

  floatx4 acc[4][4];
#pragma unroll
  for (int i = 0; i < 4; ++i)
#pragma unroll
    for (int j = 0; j < 4; ++j) acc[i][j] = (floatx4){0.f, 0.f, 0.f, 0.f};

  const float4* aptr[4];
#pragma unroll
  for (int i = 0; i < 4; ++i)
    aptr[i] = (const float4*)(embed + (size_t)tok[r0 + i * 16 + r] * HID) + q * 2;
  const uint4* bptr[4];
#pragma unroll
  for (int j = 0; j < 4; ++j)
    bptr[j] = (const uint4*)(wihI + ((size_t)d * 512 + c0 + j * 16 + r) * 64) + q;

#pragma unroll
  for (int kc = 0; kc < 4; ++kc) {
    half8_t af[4], bf[4];
#pragma unroll
    for (int i = 0; i < 4; ++i) {
      float4 x0 = aptr[i][kc * 8];
      float4 x1 = aptr[i][kc * 8 + 1];
      uint4 u;
      u.x = packh2(x0.x, x0.y); u.y = packh2(x0.z, x0.w);
      u.z = packh2(x1.x, x1.y); u.w = packh2(x1.z, x1.w);
      af[i] = __builtin_bit_cast(half8_t, u);
    }
#pragma unroll
    for (int j = 0; j < 4; ++j)
      bf[j] = __builtin_bit_cast(half8_t, bptr[j][kc * 4]);
#pragma unroll
    for (int i = 0; i < 4; ++i)
#pragma unroll
      for (int j = 0; j < 4; ++j)
        acc[i][j] = __builtin_amdgcn_mfma_f32_16x16x32_f16(af[i], bf[j], acc[i][j], 0, 0, 0);
  }

  __fp16* gat = ((__fp16*)gatex) + (size_t)d * 16384 * 512;
#pragma unroll
  for (int j = 0; j < 4; ++j) {
    int n = c0 + j * 16 + r;
    float bb = biasI[d * 512 + n];
#pragma unroll
    for (int i = 0; i < 4; ++i) {
      int rb = r0 + i * 16 + q * 4;
#pragma unroll
      for (int reg = 0; reg < 4; ++reg) {
        float v = acc[i][j][reg] + bb;
        gat[((size_t)(tl * 128 + rb + reg)) * 512 + n] = (__fp16)v;
      }
    }
  }
}

// ---------------------------------------------------------------------------
// LSTM recurrence. One WG per (d,b); grid = 256 = 1 block/CU.
// R12: pin wreg via SCALAR "+v" asm constraints (uint4 struct members) —
// R11's uint4-tied operands don't compile ("tied indirect register inputs").
// Pinned values are asm-defined -> non-rematerializable -> all 128 weight
// VGPRs must stay live across the loop (legal: 512-VGPR budget at 1 wave/EU
// with the 96 KB LDS cap).
// ---------------------------------------------------------------------------
#define PIN8(A, B) asm volatile("" : "+v"(A.x), "+v"(A.y), "+v"(A.z), "+v"(A.w), \
                                     "+v"(B.x), "+v"(B.y), "+v"(B.z), "+v"(B.w))

__global__ __launch_bounds__(256, 1) __attribute__((amdgpu_waves_per_eu(1, 1)))
void lstm_kernel(
    const uint* __restrict__ gatex, const uint* __restrict__ whh,
    const float* __restrict__ h0, const float* __restrict__ c0,
    float* __restrict__ statec, uint* __restrict__ hh, int chunk)
{
  const int wg = blockIdx.x;
  const int d = wg >> 7, b = wg & 127;
  const int tid = threadIdx.x;
  const int w = tid >> 6, lane = tid & 63;
  const int hp = lane >> 5, r = lane & 31;
  const int m = w * 32 + r;

  __shared__ __align__(16) __fp16 hist[384][128];   // 96 KB: caps 1 block/CU
  const int roff = (chunk >> 8) & 256;              // == 0, unprovable

  const uint4* wh4 = (const uint4*)(whh + (size_t)d * 512 * 64);
  uint4 wreg[4][8];
#pragma unroll
  for (int q = 0; q < 4; ++q) {
    const uint4* row = wh4 + (q * 128 + m) * 16 + hp * 8;
#pragma unroll
    for (int i = 0; i < 8; ++i) wreg[q][i] = row[i];
  }
  PIN8(wreg[0][0], wreg[0][1]); PIN8(wreg[0][2], wreg[0][3]);
  PIN8(wreg[0][4], wreg[0][5]); PIN8(wreg[0][6], wreg[0][7]);
  PIN8(wreg[1][0], wreg[1][1]); PIN8(wreg[1][2], wreg[1][3]);
  PIN8(wreg[1][4], wreg[1][5]); PIN8(wreg[1][6], wreg[1][7]);
  PIN8(wreg[2][0], wreg[2][1]); PIN8(wreg[2][2], wreg[2][3]);
  PIN8(wreg[2][4], wreg[2][5]); PIN8(wreg[2][6], wreg[2][7]);
  PIN8(wreg[3][0], wreg[3][1]); PIN8(wreg[3][2], wreg[3][3]);
  PIN8(wreg[3][4], wreg[3][5]); PIN8(wreg[3][6], wreg[3][7]);

  float c = (chunk == 0) ? c0[(size_t)(d * 128 + b) * 128 + m]
                         : statec[(size_t)(d * 128 + b) * 128 + m];

  if (tid < 64) {
    uint* h127 = (uint*)&hist[roff + 127][0];
    if (chunk == 0) {
      float2 hv = ((const float2*)(h0 + (size_t)(d * 128 + b) * 128))[tid];
      h127[tid] = packh2(hv.x, hv.y);
    } else {
      int sprev = d ? (511 - (chunk * 128 - 1)) : (chunk * 128 - 1);
      h127[tid] = hh[((size_t)(d * 512 + sprev) * 128 + b) * 64 + tid];
    }
  }
  const uint* gx0 = gatex + (size_t)d * 4194304 + (size_t)b * 256 + 2 * m;
  uint2 gx = *(const uint2*)(gx0);
  __syncthreads();

  for (int tl = 0; tl < 128; ++tl) {
    uint2 gxn = gx;
    if (tl < 127) gxn = *(const uint2*)(gx0 + (size_t)(tl + 1) * 32768);

    float a0 = 0.f, a1 = 0.f, a2 = 0.f, a3 = 0.f;
    const uint4* z4 = (const uint4*)(&hist[roff + ((tl + 127) & 127)][hp * 64]);
#pragma unroll
    for (int i = 0; i < 8; ++i) {
      uint4 z = z4[i];
      a0 = fdot2(z.x, wreg[0][i].x, a0);
      a0 = fdot2(z.y, wreg[0][i].y, a0);
      a0 = fdot2(z.z, wreg[0][i].z, a0);
      a0 = fdot2(z.w, wreg[0][i].w, a0);
      a1 = fdot2(z.x, wreg[1][i].x, a1);
      a1 = fdot2(z.y, wreg[1][i].y, a1);
      a1 = fdot2(z.z, wreg[1][i].z, a1);
      a1 = fdot2(z.w, wreg[1][i].w, a1);
      a2 = fdot2(z.x, wreg[2][i].x, a2);
      a2 = fdot2(z.y, wreg[2][i].y, a2);
      a2 = fdot2(z.z, wreg[2][i].z, a2);
      a2 = fdot2(z.w, wreg[2][i].w, a2);
      a3 = fdot2(z.x, wreg[3][i].x, a3);
      a3 = fdot2(z.y, wreg[3][i].y, a3);
      a3 = fdot2(z.z, wreg[3][i].z, a3);
      a3 = fdot2(z.w, wreg[3][i].w, a3);
    }
    a0 += __shfl_xor(a0, 32);
    a1 += __shfl_xor(a1, 32);
    a2 += __shfl_xor(a2, 32);
    a3 += __shfl_xor(a3, 32);

    half2_t g01 = __builtin_bit_cast(half2_t, gx.x);
    half2_t g23 = __builtin_bit_cast(half2_t, gx.y);
    a0 += (float)g01[0];
    a1 += (float)g01[1];
    a2 += (float)g23[0];
    a3 += (float)g23[1];

    float ig = fsig(a0);
    float fg = fsig(a1);
    float gg = ftanh(a2);
    float og = fsig(a3);
    c = fg * c + ig * gg;
    float hv = og * ftanh(c);

    if (hp == 0) hist[roff + tl][m] = (__fp16)hv;
    gx = gxn;
    __syncthreads();
  }

  statec[(size_t)(d * 128 + b) * 128 + m] = c;

  int base = chunk * 128;
  for (int i = tid; i < 2048; i += 256) {
    int sl = i >> 4, q4 = i & 15;
    int s = d ? (511 - (base + sl)) : (base + sl);
    *(uint4*)(&hh[((size_t)(d * 512 + s) * 128 + b) * 64 + q4 * 4]) =
        *(const uint4*)((const uint*)&hist[roff + sl][0] + q4 * 4);
  }
}

// ---------------------------------------------------------------------------
// Output projection (unchanged)
// ---------------------------------------------------------------------------
__global__ __launch_bounds__(256) void outproj_kernel(
    const uint* __restrict__ hh, const uint* __restrict__ woutp,
    const float* __restrict__ bout, float* __restrict__ feats)
{
  __shared__ __align__(16) uint4 zrow[8][32];
  __shared__ __align__(16) uint4 wlds[32][32];
  int tid = threadIdx.x;
  for (int j = tid; j < 1024; j += 256) {
    int k = j >> 5, i = j & 31;
    wlds[i][k] = ((const uint4*)woutp)[j];
  }
  int rl = tid >> 5, q = tid & 31;
  int row = blockIdx.x * 8 + rl;
  int b = row >> 9, s = row & 511;
  const uint4* hf4 = (const uint4*)(hh + ((size_t)s * BATCH + b) * 64);
  const uint4* hb4 = (const uint4*)(hh + ((size_t)(SEQ + s) * BATCH + b) * 64);
  zrow[rl][q] = (q < 16) ? hf4[q] : hb4[q - 16];
  __syncthreads();
  int k = q;
  float acc = bout[k];
#pragma unroll
  for (int i = 0; i < 32; ++i) {
    uint4 z = zrow[rl][i];
    uint4 wv = wlds[i][k];
    acc = fdot2(z.x, wv.x, acc);
    acc = fdot2(z.y, wv.y, acc);
    acc = fdot2(z.z, wv.z, acc);
    acc = fdot2(z.w, wv.w, acc);
  }
  feats[(size_t)row * 32 + k] = acc;
}

// ---------------------------------------------------------------------------
// CRF numerator (unchanged)
// ---------------------------------------------------------------------------
__global__ __launch_bounds__(64) void crf_num_kernel(
    const int* __restrict__ tags, const float* __restrict__ feats,
    const float* __restrict__ trans, float* __restrict__ num)
{
  int b = blockIdx.x, l = threadIdx.x;
  const int* tb = tags + b * SEQ;
  float acc = 0.f;
  for (int s = l; s < SEQ; s += 64) {
    int tg = tb[s];
    int pv = (s == 0) ? START_TAG : tb[s - 1];
    acc += trans[pv * NTAG + tg] + feats[((size_t)b * SEQ + s) * NTAG + tg];
  }
#pragma unroll
  for (int msk = 1; msk < 64; msk <<= 1) acc += __shfl_xor(acc, msk);
  if (l == 0) num[b] = acc + trans[tb[SEQ - 1] * NTAG + END_TAG];
}

// ---------------------------------------------------------------------------
// CRF stage A (unchanged)
// ---------------------------------------------------------------------------
__global__ __launch_bounds__(64) void crf_seg_kernel(
    const float* __restrict__ feats, const float* __restrict__ trans,
    uint* __restrict__ segP, float* __restrict__ segL)
{
  const float L2E = 1.4426950408889634f;
  int blk = blockIdx.x;
  int b = blk >> 5, j = blk & 31;
  int tstart = 1 + 16 * j;
  int nsteps = (j == 31) ? 15 : 16;
  int lane = threadIdx.x;
  int c = lane & 15, q = lane >> 4;

  half8_t afr[2];
#pragma unroll
  for (int rt = 0; rt < 2; ++rt) {
    const float* trow = trans + (rt * 16 + c) * 32 + q * 8;
    float e[8];
#pragma unroll
    for (int i = 0; i < 8; ++i) e[i] = fexp2(trow[i] * L2E);
    uint4 u;
    u.x = packh2(e[0], e[1]); u.y = packh2(e[2], e[3]);
    u.z = packh2(e[4], e[5]); u.w = packh2(e[6], e[7]);
    afr[rt] = __builtin_bit_cast(half8_t, u);
  }
  half8_t bfr[2];
#pragma unroll
  for (int ct = 0; ct < 2; ++ct) {
    uint4 u;
    uint vals[8];
#pragma unroll
    for (int i = 0; i < 8; ++i)
      vals[i] = ((q * 8 + i) == (ct * 16 + c)) ? 0x3C00u : 0u;
    u.x = vals[0] | (vals[1] << 16);
    u.y = vals[2] | (vals[3] << 16);
    u.z = vals[4] | (vals[5] << 16);
    u.w = vals[6] | (vals[7] << 16);
    bfr[ct] = __builtin_bit_cast(half8_t, u);
  }

  __shared__ __fp16 P16[32 * 36];

  const float* fb = feats + ((size_t)b * SEQ + tstart) * NTAG;
  float Lacc = 0.f;
  float4 pre0 = *(const float4*)(fb + q * 4);
  float4 pre1 = *(const float4*)(fb + 16 + q * 4);

  for (int s = 0; s < nsteps; ++s) {
    float4 f0 = pre0, f1 = pre1;
    if (s + 1 < nsteps) {
      pre0 = *(const float4*)(fb + (s + 1) * 32 + q * 4);
      pre1 = *(const float4*)(fb + (s + 1) * 32 + 16 + q * 4);
    }
    floatx4 z4 = (floatx4){0.f, 0.f, 0.f, 0.f};
    floatx4 c00 = __builtin_amdgcn_mfma_f32_16x16x32_f16(afr[0], bfr[0], z4, 0, 0, 0);
    floatx4 c01 = __builtin_amdgcn_mfma_f32_16x16x32_f16(afr[0], bfr[1], z4, 0, 0, 0);
    floatx4 c10 = __builtin_amdgcn_mfma_f32_16x16x32_f16(afr[1], bfr[0], z4, 0, 0, 0);
    floatx4 c11 = __builtin_amdgcn_mfma_f32_16x16x32_f16(afr[1], bfr[1], z4, 0, 0, 0);
    float pf0[4], pf1[4];
    pf0[0] = fexp2(f0.x * L2E); pf0[1] = fexp2(f0.y * L2E);
    pf0[2] = fexp2(f0.z * L2E); pf0[3] = fexp2(f0.w * L2E);
    pf1[0] = fexp2(f1.x * L2E); pf1[1] = fexp2(f1.y * L2E);
    pf1[2] = fexp2(f1.z * L2E); pf1[3] = fexp2(f1.w * L2E);
    float v00[4], v01[4], v10[4], v11[4];
#pragma unroll
    for (int rg = 0; rg < 4; ++rg) {
      v00[rg] = c00[rg] * pf0[rg];
      v01[rg] = c01[rg] * pf0[rg];
      v10[rg] = c10[rg] * pf1[rg];
      v11[rg] = c11[rg] * pf1[rg];
    }
    float mx = 0.f;
#pragma unroll
    for (int rg = 0; rg < 4; ++rg)
      mx = fmaxf(mx, fmaxf(fmaxf(v00[rg], v01[rg]), fmaxf(v10[rg], v11[rg])));
    uint ub = (uint)__builtin_amdgcn_readfirstlane((int)__builtin_bit_cast(uint, mx));
    int e = (int)((ub >> 23) & 255u);
    Lacc += (float)(e - 127);
    float sc = __builtin_bit_cast(float, (uint)((254 - e) << 23));

    __syncthreads();
    {
      uint2 wv2;
      wv2.x = packh2(v00[0] * sc, v00[1] * sc);
      wv2.y = packh2(v00[2] * sc, v00[3] * sc);
      *(uint2*)(&P16[c * 36 + q * 4]) = wv2;
      wv2.x = packh2(v10[0] * sc, v10[1] * sc);
      wv2.y = packh2(v10[2] * sc, v10[3] * sc);
      *(uint2*)(&P16[c * 36 + 16 + q * 4]) = wv2;
      wv2.x = packh2(v01[0] * sc, v01[1] * sc);
      wv2.y = packh2(v01[2] * sc, v01[3] * sc);
      *(uint2*)(&P16[(16 + c) * 36 + q * 4]) = wv2;
      wv2.x = packh2(v11[0] * sc, v11[1] * sc);
      wv2.y = packh2(v11[2] * sc, v11[3] * sc);
      *(uint2*)(&P16[(16 + c) * 36 + 16 + q * 4]) = wv2;
    }
    __syncthreads();
    {
      uint2 lo0 = *(const uint2*)(&P16[c * 36 + q * 8]);
      uint2 hi0 = *(const uint2*)(&P16[c * 36 + q * 8 + 4]);
      uint4 u0; u0.x = lo0.x; u0.y = lo0.y; u0.z = hi0.x; u0.w = hi0.y;
      bfr[0] = __builtin_bit_cast(half8_t, u0);
      uint2 lo1 = *(const uint2*)(&P16[(16 + c) * 36 + q * 8]);
      uint2 hi1 = *(const uint2*)(&P16[(16 + c) * 36 + q * 8 + 4]);
      uint4 u1; u1.x = lo1.x; u1.y = lo1.y; u1.z = hi1.x; u1.w = hi1.y;
      bfr[1] = __builtin_bit_cast(half8_t, u1);
    }
  }
  __syncthreads();
  uint* gp = segP + (size_t)blk * 512;
  if (lane < 32) {
    int i = lane;
#pragma unroll
    for (int tp = 0; tp < 16; ++tp) {
      uint lo = (uint)__builtin_bit_cast(unsigned short, P16[(2 * tp) * 36 + i]);
      uint hi = (uint)__builtin_bit_cast(unsigned short, P16[(2 * tp + 1) * 36 + i]);
      gp[i * 16 + tp] = lo | (hi << 16);
    }
  }
  if (lane == 0) segL[blk] = Lacc;
}

// ---------------------------------------------------------------------------
// CRF stage B (unchanged)
// ---------------------------------------------------------------------------
__global__ __launch_bounds__(64) void crf_comb_kernel(
    const float* __restrict__ feats, const float* __restrict__ trans,
    const uint* __restrict__ segP, const float* __restrict__ segL,
    float* __restrict__ den)
{
  const float L2E = 1.4426950408889634f, LN2 = 0.6931471805599453f;
  int b = blockIdx.x, l = threadIdx.x;
  int i = l & 31, hp = l >> 5;
  const float* fb = feats + (size_t)b * SEQ * NTAG;

  float sT = 0.f;
  for (int p = 0; p < 32; ++p) sT += fexp2(trans[i * 32 + p] * L2E);
  float v = (1.f + sT) * fexp2(fb[i] * L2E);
  float L = -10000.f * L2E;

  float vo = __shfl_xor(v, 1);
  uint pv = (i & 1) ? packh2(vo, v) : packh2(v, vo);

  const uint* gp0 = segP + (size_t)b * 32 * 512 + i * 16 + hp * 8;
  uint4 ra = *(const uint4*)(gp0);
  uint4 rb = *(const uint4*)(gp0 + 4);

  for (int seg = 0; seg < 32; ++seg) {
    uint4 ca = ra, cb = rb;
    if (seg + 1 < 32) {
      ra = *(const uint4*)(gp0 + (seg + 1) * 512);
      rb = *(const uint4*)(gp0 + (seg + 1) * 512 + 4);
    }
    float g0 = __shfl(__builtin_bit_cast(float, pv), hp * 16 + 0);
    float g1 = __shfl(__builtin_bit_cast(float, pv), hp * 16 + 2);
    float g2 = __shfl(__builtin_bit_cast(float, pv), hp * 16 + 4);
    float g3 = __shfl(__builtin_bit_cast(float, pv), hp * 16 + 6);
    float g4 = __shfl(__builtin_bit_cast(float, pv), hp * 16 + 8);
    float g5 = __shfl(__builtin_bit_cast(float, pv), hp * 16 + 10);
    float g6 = __shfl(__builtin_bit_cast(float, pv), hp * 16 + 12);
    float g7 = __shfl(__builtin_bit_cast(float, pv), hp * 16 + 14);
    float acc = 0.f;
    acc = fdot2(__builtin_bit_cast(uint, g0), ca.x, acc);
    acc = fdot2(__builtin_bit_cast(uint, g1), ca.y, acc);
    acc = fdot2(__builtin_bit_cast(uint, g2), ca.z, acc);
    acc = fdot2(__builtin_bit_cast(uint, g3), ca.w, acc);
    acc = fdot2(__builtin_bit_cast(uint, g4), cb.x, acc);
    acc = fdot2(__builtin_bit_cast(uint, g5), cb.y, acc);
    acc = fdot2(__builtin_bit_cast(uint, g6), cb.z, acc);
    acc = fdot2(__builtin_bit_cast(uint, g7), cb.w, acc);
    float sm = acc + __shfl_xor(acc, 32);
    uint ub = (uint)__builtin_amdgcn_readfirstlane((int)__builtin_bit_cast(uint, sm));
    int e = (int)((ub >> 23) & 255u);
    L += (float)(e - 127) + segL[b * 32 + seg];
    float sc = __builtin_bit_cast(float, (uint)((254 - e) << 23));
    v = sm * sc;
    float vo2 = __shfl_xor(v, 1);
    pv = (i & 1) ? packh2(vo2, v) : packh2(v, vo2);
  }
  float wv = v * fexp2(trans[i * 32 + END_TAG] * L2E);
#pragma unroll
  for (int msk = 1; msk <= 16; msk <<= 1) wv += __shfl_xor(wv, msk);
  if (l == 0) den[b] = (L + flog2(wv)) * LN2;
}

__global__ __launch_bounds__(128) void final_kernel(
    const float* __restrict__ num, const float* __restrict__ den,
    float* __restrict__ out)
{
  int tid = threadIdx.x;
  float v = num[tid] - den[tid];
#pragma unroll
  for (int msk = 1; msk < 64; msk <<= 1) v += __shfl_xor(v, msk);
  __shared__ float tmp[2];
  if ((tid & 63) == 0) tmp[tid >> 6] = v;
  __syncthreads();
  if (tid == 0) out[0] = (tmp[0] + tmp[1]) * (1.f / 128.f);
}

// ---------------------------------------------------------------------------
// Workspace layout (bytes): same as R8 (~51.4 MB)
// ---------------------------------------------------------------------------
extern "C" void kernel_launch(void* const* d_in, const int* in_sizes, int n_in,
                              void* d_out, int out_size, void* d_ws, size_t ws_size,
                              hipStream_t stream)
{
  const int* sentence = (const int*)d_in[0];
  const int* tags = (const int*)d_in[1];
  const float* embed = (const float*)d_in[2];
  const float* Wihf = (const float*)d_in[3];
  const float* Whhf = (const float*)d_in[4];
  const float* bihf = (const float*)d_in[5];
  const float* bhhf = (const float*)d_in[6];
  const float* Wihb = (const float*)d_in[7];
  const float* Whhb = (const float*)d_in[8];
  const float* bihb = (const float*)d_in[9];
  const float* bhhb = (const float*)d_in[10];
  const float* Wout = (const float*)d_in[11];
  const float* bout = (const float*)d_in[12];
  const float* trans = (const float*)d_in[13];
  const float* h0 = (const float*)d_in[14];
  const float* c0 = (const float*)d_in[15];
  float* out = (float*)d_out;

  char* ws = (char*)d_ws;
  uint* wihI = (uint*)(ws + 0);
  uint* whh = (uint*)(ws + 262144);
  uint* woutp = (uint*)(ws + 524288);
  float* biasI = (float*)(ws + 540672);
  float* numb = (float*)(ws + 544768);
  float* denb = (float*)(ws + 545280);
  float* statec = (float*)(ws + 545792);
  uint* hh = (uint*)(ws + 1048576);
  uint* gatex = (uint*)(ws + 34603008);
  float* feats = (float*)(ws + 34603008);
  uint* segP = (uint*)(ws + 42991616);
  float* segL = (float*)(ws + 51380224);

  hipLaunchKernelGGL(prep_kernel, dim3(532), dim3(256), 0, stream,
                     Wihf, Whhf, bihf, bhhf, Wihb, Whhb, bihb, bhhb, Wout,
                     wihI, whh, woutp, biasI);
  for (int c = 0; c < 4; ++c) {
    hipLaunchKernelGGL(gemmx_kernel, dim3(1024), dim3(256), 0, stream,
                       sentence, embed, wihI, biasI, gatex, c);
    hipLaunchKernelGGL(lstm_kernel, dim3(256), dim3(256), 0, stream,
                       gatex, whh, h0, c0, statec, hh, c);
  }
  hipLaunchKernelGGL(outproj_kernel, dim3(8192), dim3(256), 0, stream,
                     hh, woutp, bout, feats);
  hipLaunchKernelGGL(crf_num_kernel, dim3(128), dim3(64), 0, stream,
                     tags, feats, trans, numb);
  hipLaunchKernelGGL(crf_seg_kernel, dim3(4096), dim3(64), 0, stream,
                     feats, trans, segP, segL);
  hipLaunchKernelGGL(crf_comb_kernel, dim3(128), dim3(64), 0, stream,
                     feats, trans, segP, segL, denb);
  hipLaunchKernelGGL(final_kernel, dim3(1), dim3(128), 0, stream,
                     numb, denb, out);
}